// Round 14
// baseline (11021.284 us; speedup 1.0000x reference)
//
#include <hip/hip_runtime.h>
#include <hip/hip_bf16.h>

#define TT 2048
#define DIM 1024
#define HFF 8192
#define NBATCH 4
#define PWG 32
#define THRESH 0.05f

typedef __bf16 bf16x8 __attribute__((ext_vector_type(8)));
typedef float f32x4 __attribute__((ext_vector_type(4)));
typedef int i32x4 __attribute__((ext_vector_type(4)));

__device__ __forceinline__ unsigned short f2bf(float f) {
    __hip_bfloat16 h = __float2bfloat16(f);
    return __builtin_bit_cast(unsigned short, h);
}
__device__ __forceinline__ float bf2f(unsigned short u) {
    return __bfloat162float(__builtin_bit_cast(__hip_bfloat16, u));
}
__device__ __forceinline__ bf16x8 ldf(const unsigned short* p) {
    return *reinterpret_cast<const bf16x8*>(p);
}

// MALL-coherent (cross-XCD) 16B load: bypass L1 (sc0) and L2 (sc1).
__device__ __forceinline__ void ld2x4_mall(const float* p0, const float* p1,
                                           f32x4* a, f32x4* b) {
    asm volatile("global_load_dwordx4 %0, %2, off sc0 sc1\n\t"
                 "global_load_dwordx4 %1, %3, off sc0 sc1\n\t"
                 "s_waitcnt vmcnt(0)"
                 : "=&v"(*a), "=&v"(*b) : "v"(p0), "v"(p1) : "memory");
}
__device__ __forceinline__ i32x4 ld4_mall(const int* p) {
    i32x4 v;
    asm volatile("global_load_dwordx4 %0, %1, off sc0 sc1\n\t"
                 "s_waitcnt vmcnt(0)"
                 : "=&v"(v) : "v"(p) : "memory");
    return v;
}

// async global->LDS, 16B per lane; LDS dest = (uniform base) + lane*16
__device__ __forceinline__ void gload_lds16(const void* g, void* l) {
    __builtin_amdgcn_global_load_lds(
        (const __attribute__((address_space(1))) unsigned int*)g,
        (__attribute__((address_space(3))) unsigned int*)l, 16, 0, 0);
}

// ---------------- mask dtype probe: 1 = int32 mask, 0 = uint8 mask ----------
__global__ void maskprobe_k(const unsigned int* mask_words, int* flag) {
    __shared__ int allok;
    if (threadIdx.x == 0) allok = 1;
    __syncthreads();
    int ok = 1;
    for (int i = 0; i < 16; ++i) {
        unsigned int w = mask_words[threadIdx.x * 16 + i];
        if (w > 1u) ok = 0;
    }
    if (!ok) atomicAnd(&allok, 0);
    __syncthreads();
    if (threadIdx.x == 0) flag[0] = allok;
}

// ---------------- w_eff = syn_w * mask  -> bf16 ----------------
__global__ void weff_k(const float* __restrict__ synw, const void* __restrict__ mask,
                       const int* __restrict__ flag, unsigned short* __restrict__ dst) {
    const int isInt = flag[0];
    const int n = DIM * DIM;
    for (int i = blockIdx.x * 256 + threadIdx.x; i < n; i += gridDim.x * 256) {
        bool m;
        if (isInt) m = ((const int*)mask)[i] != 0;
        else       m = ((const unsigned char*)mask)[i] != 0;
        dst[i] = f2bf(m ? synw[i] : 0.f);
    }
}

// ---------------- f32 -> bf16 convert ----------------
__global__ void conv_k(const float* __restrict__ src, unsigned short* __restrict__ dst, int n) {
    for (int i = blockIdx.x * 256 + threadIdx.x; i < n; i += gridDim.x * 256)
        dst[i] = f2bf(src[i]);
}

// ---------------- f32 -> bf16 hi/lo split ----------------
__global__ void split_k(const float* __restrict__ src, unsigned short* __restrict__ hi,
                        unsigned short* __restrict__ lo, int n) {
    for (int i = blockIdx.x * 256 + threadIdx.x; i < n; i += gridDim.x * 256) {
        float v = src[i];
        unsigned short h = f2bf(v);
        hi[i] = h;
        lo[i] = f2bf(v - bf2f(h));
    }
}

// ---------------- spike bit expansion: u32 bits -> bf16 {0,1} ----------------
__global__ void spkexp_k(const unsigned int* __restrict__ spk, unsigned short* __restrict__ sbf) {
    const int i = blockIdx.x * 256 + threadIdx.x;   // 4*64*1024 words
    const unsigned int w = spk[i];
    const int d = i & 1023, t32 = (i >> 10) & 63, b = i >> 16;
    const size_t base = ((size_t)b * TT + (size_t)t32 * 32) * DIM + d;
    #pragma unroll
    for (int j = 0; j < 32; ++j)
        sbf[base + (size_t)j * DIM] = ((w >> j) & 1u) ? (unsigned short)0x3F80 : (unsigned short)0;
}

// ---------------- rmsnorm; SPLIT: also emit lo residual ----------------
template <bool SPLIT>
__global__ void rms_k(const float* __restrict__ xin, const float* __restrict__ w,
                      unsigned short* __restrict__ hi, unsigned short* __restrict__ lo) {
    const int row = blockIdx.x;
    const int tid = threadIdx.x;
    const float4 xv = *reinterpret_cast<const float4*>(xin + (size_t)row * DIM + tid * 4);
    float ss = xv.x * xv.x + xv.y * xv.y + xv.z * xv.z + xv.w * xv.w;
    #pragma unroll
    for (int m = 1; m <= 32; m <<= 1) ss += __shfl_xor(ss, m);
    __shared__ float red[5];
    if ((tid & 63) == 0) red[tid >> 6] = ss;
    __syncthreads();
    if (tid == 0) {
        float s = red[0] + red[1] + red[2] + red[3];
        red[4] = 1.f / sqrtf(s * (1.f / DIM) + 1e-6f);
    }
    __syncthreads();
    const float scale = red[4];
    const float wv[4] = {w[tid*4], w[tid*4+1], w[tid*4+2], w[tid*4+3]};
    const float xa[4] = {xv.x, xv.y, xv.z, xv.w};
    #pragma unroll
    for (int i = 0; i < 4; ++i) {
        float v = xa[i] * scale * wv[i];
        unsigned short h = f2bf(v);
        hi[(size_t)row * DIM + tid * 4 + i] = h;
        if constexpr (SPLIT) lo[(size_t)row * DIM + tid * 4 + i] = f2bf(v - bf2f(h));
    }
}

// ---------------- LDS-staged MFMA GEMM (m97 structure): C = A @ B^T --------
// 128x128 tile, BK=64, 4 waves, global_load_lds width-16 staging (linear LDS
// dest = uniform base + lane*16; per-lane global src), ds_read_b128 frags.
// EPI 0: U = hilo(A,B1) + liq_b, (T,B,D) transpose write   [HILO]
// EPI 1: x2 = aux1 + acc1*sigmoid(acc2+aux2)               [DUAL]
// EPI 2: hbf = bf16(silu(acc1)*acc2)                       [DUAL]
// EPI 3: out = aux1 + acc1                                 [single]
template <int EPI>
__global__ __launch_bounds__(256, 1) void gemm2_k(
    const unsigned short* __restrict__ A,  const unsigned short* __restrict__ Alo,
    const unsigned short* __restrict__ B1, const unsigned short* __restrict__ B1lo,
    const unsigned short* __restrict__ B2,
    const float* __restrict__ aux1, const float* __restrict__ aux2,
    float* __restrict__ outf, unsigned short* __restrict__ outbf,
    int N, int K) {
    constexpr bool HILO = (EPI == 0);
    constexpr bool DUAL = (EPI == 1 || EPI == 2);
    __shared__ unsigned short sA[128 * 64];
    __shared__ unsigned short sB1[128 * 64];
    __shared__ unsigned short sAlo[HILO ? 128 * 64 : 8];
    __shared__ unsigned short sBlo[HILO ? 128 * 64 : 8];
    __shared__ unsigned short sB2[DUAL ? 128 * 64 : 8];
    const int lane = threadIdx.x & 63;
    const int wv = threadIdx.x >> 6;
    const int l15 = lane & 15, l4 = lane >> 4;
    const long row0 = (long)blockIdx.y * 128;
    const long col0 = (long)blockIdx.x * 128;
    const int wr = wv >> 1, wc = wv & 1;
    // staging geometry: chunk = wv*4+i covers tile rows chunk*8..+8 (128B/row)
    const int crow = lane >> 3;               // row within chunk
    const int cbyte = (lane & 7) * 16;        // byte within row
    f32x4 acc[4][4];
    f32x4 acc2[DUAL ? 4 : 1][DUAL ? 4 : 1];
    #pragma unroll
    for (int i = 0; i < 4; ++i)
        #pragma unroll
        for (int j = 0; j < 4; ++j) {
            acc[i][j] = (f32x4){0.f, 0.f, 0.f, 0.f};
            if constexpr (DUAL) acc2[i][j] = (f32x4){0.f, 0.f, 0.f, 0.f};
        }
    for (int kt = 0; kt < K; kt += 64) {
        #pragma unroll
        for (int i = 0; i < 4; ++i) {
            const int chunk = wv * 4 + i;
            const int trow = chunk * 8 + crow;
            const size_t goffA = ((row0 + trow) * (size_t)K + kt) * 2 + cbyte;
            const size_t goffB = ((col0 + trow) * (size_t)K + kt) * 2 + cbyte;
            gload_lds16((const char*)A + goffA, (char*)sA + chunk * 1024);
            gload_lds16((const char*)B1 + goffB, (char*)sB1 + chunk * 1024);
            if constexpr (HILO) {
                gload_lds16((const char*)Alo + goffA, (char*)sAlo + chunk * 1024);
                gload_lds16((const char*)B1lo + goffB, (char*)sBlo + chunk * 1024);
            }
            if constexpr (DUAL)
                gload_lds16((const char*)B2 + goffB, (char*)sB2 + chunk * 1024);
        }
        __syncthreads();   // drains vmcnt: staged data visible
        #pragma unroll
        for (int kk2 = 0; kk2 < 64; kk2 += 32) {
            bf16x8 af[4], bf_[4], al[4], bl[4], b2f[4];
            #pragma unroll
            for (int i = 0; i < 4; ++i) {
                const int ao = (wr * 64 + i * 16 + l15) * 64 + kk2 + l4 * 8;
                const int bo = (wc * 64 + i * 16 + l15) * 64 + kk2 + l4 * 8;
                af[i]  = ldf(sA + ao);
                bf_[i] = ldf(sB1 + bo);
                if constexpr (HILO) { al[i] = ldf(sAlo + ao); bl[i] = ldf(sBlo + bo); }
                if constexpr (DUAL) b2f[i] = ldf(sB2 + bo);
            }
            #pragma unroll
            for (int i = 0; i < 4; ++i)
                #pragma unroll
                for (int j = 0; j < 4; ++j) {
                    acc[i][j] = __builtin_amdgcn_mfma_f32_16x16x32_bf16(af[i], bf_[j], acc[i][j], 0, 0, 0);
                    if constexpr (HILO) {
                        acc[i][j] = __builtin_amdgcn_mfma_f32_16x16x32_bf16(af[i], bl[j], acc[i][j], 0, 0, 0);
                        acc[i][j] = __builtin_amdgcn_mfma_f32_16x16x32_bf16(al[i], bf_[j], acc[i][j], 0, 0, 0);
                    }
                    if constexpr (DUAL)
                        acc2[i][j] = __builtin_amdgcn_mfma_f32_16x16x32_bf16(af[i], b2f[j], acc2[i][j], 0, 0, 0);
                }
        }
        __syncthreads();   // WAR: compute done before next stage overwrites
    }
    #pragma unroll
    for (int i = 0; i < 4; ++i) {
        #pragma unroll
        for (int r = 0; r < 4; ++r) {
            const long row = row0 + wr * 64 + i * 16 + l4 * 4 + r;
            #pragma unroll
            for (int j = 0; j < 4; ++j) {
                const long col = col0 + wc * 64 + j * 16 + l15;
                float v = acc[i][j][r];
                if constexpr (EPI == 0) {
                    int m = (int)row;
                    int bb = m >> 11, tt = m & 2047;
                    outf[((size_t)(tt * NBATCH + bb)) * DIM + col] = v + aux1[col];
                } else if constexpr (EPI == 1) {
                    size_t idx = (size_t)row * N + col;
                    float gg = acc2[i][j][r] + aux2[col];
                    outf[idx] = aux1[idx] + v * (1.f / (1.f + expf(-gg)));
                } else if constexpr (EPI == 2) {
                    size_t idx = (size_t)row * N + col;
                    float u = acc2[i][j][r];
                    outbf[idx] = f2bf((v / (1.f + expf(-v))) * u);
                } else {
                    size_t idx = (size_t)row * N + col;
                    outf[idx] = aux1[idx] + v;
                }
            }
        }
    }
}

// ---------------- liquid recurrence + PLIF, 32 co-resident WGs --------------
// R9 memory ops; chain shortened: PER-WAVE flags (flags[wg*8+g]) published
// right after each wave's own vmcnt drain (no barrier-1, no tid0 hop).
// Wave 0 alone polls all 256 flags: lane L reads flags[4L..4L+3] (one
// dwordx4) -> __all over 64 lanes. 32 pollers total (R10 proved more
// pollers congest the MALL). WAR safety: wave publishes t+1 only after its
// hl reads + h stores complete; all-256 observed => all reads of hg[t&1]
// and hl done everywhere => refill overwrite safe (R9 induction).
// LDS h layout (bijective, 16B aligned): word(b,k) = b*1088 + (k>>6)*68 + (k&63)
__global__ __launch_bounds__(512, 1) void recur_k(
    const float* __restrict__ wrec, const float* __restrict__ U,
    const float* __restrict__ liqtau, const float* __restrict__ plifw,
    float* __restrict__ hg, int* __restrict__ flags, unsigned int* __restrict__ spk) {
    const int tid = threadIdx.x;
    const int wg = blockIdx.x;
    const int g = tid >> 6;
    const int L = tid & 63;
    const int kp = L;
    const int d0 = wg * 32 + g * 4;

    float wreg[4][16];
    #pragma unroll
    for (int d = 0; d < 4; ++d) {
        const float* wr = wrec + (size_t)(d0 + d) * DIM + kp * 16;
        #pragma unroll
        for (int q = 0; q < 4; ++q) {
            f32x4 w4 = *reinterpret_cast<const f32x4*>(wr + q * 4);
            wreg[d][q*4+0] = w4[0]; wreg[d][q*4+1] = w4[1];
            wreg[d][q*4+2] = w4[2]; wreg[d][q*4+3] = w4[3];
        }
    }

    __shared__ float hl[4 * 1088];
    for (int i = tid; i < 4 * 1088; i += 512) hl[i] = 0.f;

    const int od = L >> 2, ob = L & 3;
    const int odim = d0 + od;
    const bool own = (L < 16);
    float hq = 0.f, vq = 0.f, tauv = 1.f;
    unsigned smask = 0u;
    const float decay = 1.f / (1.f + expf(-plifw[0]));
    if (own) {
        float lt = liqtau[odim];
        tauv = (lt > 20.f) ? lt : log1pf(expf(lt));
    }
    const int sel1 = L & 1, sel2 = (L >> 1) & 1, sel4 = (L >> 2) & 1, sel8 = (L >> 3) & 1;

    int cb[4];
    #pragma unroll
    for (int b = 0; b < 4; ++b)
        cb[b] = b * 1088 + (kp >> 2) * 68 + (kp & 3) * 16;
    const int* fp = flags + L * 4;   // poll: lane L covers flags[4L..4L+3]
    __syncthreads();

    for (int t = 0; t < TT; ++t) {
        float uvp = 0.f;
        if (own) uvp = U[((size_t)t * NBATCH + ob) * DIM + odim];

        float a[16];
        #pragma unroll
        for (int v = 0; v < 16; ++v) a[v] = 0.f;
        #pragma unroll
        for (int q = 0; q < 4; ++q) {
            const f32x4 h0 = *reinterpret_cast<const f32x4*>(hl + cb[0] + q * 4);
            const f32x4 h1 = *reinterpret_cast<const f32x4*>(hl + cb[1] + q * 4);
            const f32x4 h2 = *reinterpret_cast<const f32x4*>(hl + cb[2] + q * 4);
            const f32x4 h3 = *reinterpret_cast<const f32x4*>(hl + cb[3] + q * 4);
            #pragma unroll
            for (int d = 0; d < 4; ++d)
                #pragma unroll
                for (int e = 0; e < 4; ++e) {
                    const float w = wreg[d][q * 4 + e];
                    a[d*4+0] = fmaf(w, h0[e], a[d*4+0]);
                    a[d*4+1] = fmaf(w, h1[e], a[d*4+1]);
                    a[d*4+2] = fmaf(w, h2[e], a[d*4+2]);
                    a[d*4+3] = fmaf(w, h3[e], a[d*4+3]);
                }
        }
        // butterfly-scatter reduce: lane L ends with sum_lanes(a[L&15]) in a[0]
        #pragma unroll
        for (int j = 0; j < 8; ++j) {
            float snd = sel1 ? a[2*j] : a[2*j+1];
            float kept = sel1 ? a[2*j+1] : a[2*j];
            a[j] = kept + __shfl_xor(snd, 1);
        }
        #pragma unroll
        for (int j = 0; j < 4; ++j) {
            float snd = sel2 ? a[2*j] : a[2*j+1];
            float kept = sel2 ? a[2*j+1] : a[2*j];
            a[j] = kept + __shfl_xor(snd, 2);
        }
        #pragma unroll
        for (int j = 0; j < 2; ++j) {
            float snd = sel4 ? a[2*j] : a[2*j+1];
            float kept = sel4 ? a[2*j+1] : a[2*j];
            a[j] = kept + __shfl_xor(snd, 4);
        }
        {
            float snd = sel8 ? a[0] : a[1];
            float kept = sel8 ? a[1] : a[0];
            a[0] = kept + __shfl_xor(snd, 8);
        }
        a[0] += __shfl_xor(a[0], 16);
        a[0] += __shfl_xor(a[0], 32);

        if (own) {
            float pre = a[0] + uvp;
            float th = tanhf(pre);
            float hn = hq + (th - hq) / tauv;
            hq = hn;
            float v = vq + decay * (hn - vq);
            float s = ((v - THRESH) > 0.f) ? 1.f : 0.f;
            vq = v - s * THRESH;
            smask |= (s > 0.f ? 1u : 0u) << (t & 31);
            if ((t & 31) == 31) {
                __hip_atomic_store(&spk[ob * 65536 + (t >> 5) * 1024 + odim], smask,
                                   __ATOMIC_RELAXED, __HIP_MEMORY_SCOPE_SYSTEM);
                smask = 0u;
            }
            // write-through to MALL (sc0 sc1)
            __hip_atomic_store(&hg[(size_t)(t & 1) * 4096 + ob * 1024 + odim], hn,
                               __ATOMIC_RELAXED, __HIP_MEMORY_SCOPE_SYSTEM);
        }
        if (t == TT - 1) break;
        // per-wave: drain own stores to MALL, publish own flag (no barrier-1)
        asm volatile("s_waitcnt vmcnt(0)" ::: "memory");
        if (L == 0)
            __hip_atomic_store(&flags[wg * 8 + g], t + 1,
                               __ATOMIC_RELAXED, __HIP_MEMORY_SCOPE_SYSTEM);
        if (g == 0) {
            // single poller per WG: 64 lanes x 4 flags = all 256 per-wave flags
            while (true) {
                i32x4 f = ld4_mall(fp);
                bool ok = (f[0] >= t + 1) & (f[1] >= t + 1) &
                          (f[2] >= t + 1) & (f[3] >= t + 1);
                if (__all(ok)) break;
            }
        }
        __syncthreads();  // release all waves for refill
        {
            const float* src = hg + (size_t)(t & 1) * 4096;
            const int b = tid >> 7, k0 = (tid & 127) * 8;
            const int w = b * 1088 + (k0 >> 6) * 68 + (k0 & 63);
            f32x4 va, vb;
            ld2x4_mall(src + b * 1024 + k0, src + b * 1024 + k0 + 4, &va, &vb);
            *reinterpret_cast<f32x4*>(hl + w) = va;
            *reinterpret_cast<f32x4*>(hl + w + 4) = vb;
        }
        __syncthreads();
    }
}

extern "C" void kernel_launch(void* const* d_in, const int* in_sizes, int n_in,
                              void* d_out, int out_size, void* d_ws, size_t ws_size,
                              hipStream_t stream) {
    (void)in_sizes; (void)n_in; (void)out_size;
    const float* x     = (const float*)d_in[0];
    const float* ln1   = (const float*)d_in[1];
    const float* win   = (const float*)d_in[2];
    const float* wrec  = (const float*)d_in[3];
    const float* liqb  = (const float*)d_in[4];
    const float* liqtau= (const float*)d_in[5];
    const float* plifw = (const float*)d_in[6];
    const float* synw  = (const float*)d_in[7];
    const float* gatew = (const float*)d_in[8];
    const float* gateb = (const float*)d_in[9];
    const float* ln2   = (const float*)d_in[10];
    const float* wgp   = (const float*)d_in[11];
    const float* wup   = (const float*)d_in[12];
    const float* wdp   = (const float*)d_in[13];
    const void*  mask  = d_in[14];
    float* dout = (float*)d_out;
    char* ws = (char*)d_ws;
    const size_t MB = (size_t)1 << 20;

    unsigned short* winh  = (unsigned short*)(ws + 0 * MB);
    unsigned short* winl  = (unsigned short*)(ws + 2 * MB);
    unsigned short* weffb = (unsigned short*)(ws + 4 * MB);
    unsigned short* gatewb= (unsigned short*)(ws + 6 * MB);
    unsigned short* wgb   = (unsigned short*)(ws + 8 * MB);
    unsigned short* wub   = (unsigned short*)(ws + 24 * MB);
    unsigned short* wdb   = (unsigned short*)(ws + 40 * MB);
    unsigned short* ahi   = (unsigned short*)(ws + 56 * MB);   // reused as y_bf
    unsigned short* alo   = (unsigned short*)(ws + 72 * MB);
    float*          Ubuf  = (float*)(ws + 88 * MB);            // reused as hff chunk
    unsigned short* hffb  = (unsigned short*)(ws + 88 * MB);
    unsigned short* sbf   = (unsigned short*)(ws + 120 * MB);
    float*          x2    = (float*)(ws + 136 * MB);
    float*          hgb   = (float*)(ws + 168 * MB);           // 32 KB
    int*            flags = (int*)(ws + 168 * MB + 64 * 1024); // 1 KB (256 flags)
    int*            flag  = (int*)(ws + 168 * MB + 80 * 1024);
    unsigned int*   spk   = (unsigned int*)(ws + 169 * MB);    // 1 MB
    unsigned short* hfull = (unsigned short*)(ws + 171 * MB);  // 128 MiB if avail
    const bool FULLFFN = (ws_size >= 306 * MB);

    hipMemsetAsync(flags, 0, 1024, stream);
    maskprobe_k<<<1, 256, 0, stream>>>((const unsigned int*)mask, flag);
    weff_k<<<1024, 256, 0, stream>>>(synw, mask, flag, weffb);
    split_k<<<1024, 256, 0, stream>>>(win, winh, winl, DIM * DIM);
    conv_k<<<1024, 256, 0, stream>>>(gatew, gatewb, DIM * DIM);
    conv_k<<<2048, 256, 0, stream>>>(wgp, wgb, HFF * DIM);
    conv_k<<<2048, 256, 0, stream>>>(wup, wub, HFF * DIM);
    conv_k<<<2048, 256, 0, stream>>>(wdp, wdb, DIM * HFF);

    rms_k<true><<<NBATCH * TT, 256, 0, stream>>>(x, ln1, ahi, alo);
    gemm2_k<0><<<dim3(DIM / 128, (NBATCH * TT) / 128), 256, 0, stream>>>(
        ahi, alo, winh, winl, nullptr, liqb, nullptr, Ubuf, nullptr, DIM, DIM);

    recur_k<<<PWG, 512, 0, stream>>>(wrec, Ubuf, liqtau, plifw, hgb, flags, spk);
    spkexp_k<<<(NBATCH * 64 * 1024) / 256, 256, 0, stream>>>(spk, sbf);

    gemm2_k<1><<<dim3(DIM / 128, (NBATCH * TT) / 128), 256, 0, stream>>>(
        sbf, nullptr, weffb, nullptr, gatewb, x, gateb, x2, nullptr, DIM, DIM);

    rms_k<false><<<NBATCH * TT, 256, 0, stream>>>(x2, ln2, ahi, nullptr);

    if (FULLFFN) {
        gemm2_k<2><<<dim3(HFF / 128, (NBATCH * TT) / 128), 256, 0, stream>>>(
            ahi, nullptr, wgb, nullptr, wub, nullptr, nullptr,
            nullptr, hfull, HFF, DIM);
        gemm2_k<3><<<dim3(DIM / 128, (NBATCH * TT) / 128), 256, 0, stream>>>(
            hfull, nullptr, wdb, nullptr, nullptr, x2, nullptr,
            dout, nullptr, DIM, HFF);
    } else {
        const int CH = 2048;  // fallback: chunked FFN bounded to 32 MB scratch
        for (int c = 0; c < (NBATCH * TT) / CH; ++c) {
            const size_t ro = (size_t)c * CH;
            gemm2_k<2><<<dim3(HFF / 128, CH / 128), 256, 0, stream>>>(
                ahi + ro * DIM, nullptr, wgb, nullptr, wub, nullptr, nullptr,
                nullptr, hffb, HFF, DIM);
            gemm2_k<3><<<dim3(DIM / 128, CH / 128), 256, 0, stream>>>(
                hffb, nullptr, wdb, nullptr, nullptr, x2 + ro * DIM, nullptr,
                dout + ro * DIM, nullptr, DIM, HFF);
        }
    }
}

// Round 15
// 9119.678 us; speedup vs baseline: 1.2085x; 1.2085x over previous
//
#include <hip/hip_runtime.h>
#include <hip/hip_bf16.h>

#define TT 2048
#define DIM 1024
#define HFF 8192
#define NBATCH 4
#define PWG 64
#define THRESH 0.05f

typedef __bf16 bf16x8 __attribute__((ext_vector_type(8)));
typedef float f32x4 __attribute__((ext_vector_type(4)));

__device__ __forceinline__ unsigned short f2bf(float f) {
    __hip_bfloat16 h = __float2bfloat16(f);
    return __builtin_bit_cast(unsigned short, h);
}
__device__ __forceinline__ float bf2f(unsigned short u) {
    return __bfloat162float(__builtin_bit_cast(__hip_bfloat16, u));
}
__device__ __forceinline__ bf16x8 ldf(const unsigned short* p) {
    return *reinterpret_cast<const bf16x8*>(p);
}

// MALL-coherent (cross-XCD) 16B load: bypass L1 (sc0) and L2 (sc1).
__device__ __forceinline__ void ld1x4_mall(const float* p, f32x4* a) {
    asm volatile("global_load_dwordx4 %0, %1, off sc0 sc1\n\t"
                 "s_waitcnt vmcnt(0)"
                 : "=&v"(*a) : "v"(p) : "memory");
}

// async global->LDS, 16B per lane; LDS dest = (uniform base) + lane*16
__device__ __forceinline__ void gload_lds16(const void* g, void* l) {
    __builtin_amdgcn_global_load_lds(
        (const __attribute__((address_space(1))) unsigned int*)g,
        (__attribute__((address_space(3))) unsigned int*)l, 16, 0, 0);
}

// ---------------- mask dtype probe: 1 = int32 mask, 0 = uint8 mask ----------
__global__ void maskprobe_k(const unsigned int* mask_words, int* flag) {
    __shared__ int allok;
    if (threadIdx.x == 0) allok = 1;
    __syncthreads();
    int ok = 1;
    for (int i = 0; i < 16; ++i) {
        unsigned int w = mask_words[threadIdx.x * 16 + i];
        if (w > 1u) ok = 0;
    }
    if (!ok) atomicAnd(&allok, 0);
    __syncthreads();
    if (threadIdx.x == 0) flag[0] = allok;
}

// ---------------- w_eff = syn_w * mask  -> bf16 ----------------
__global__ void weff_k(const float* __restrict__ synw, const void* __restrict__ mask,
                       const int* __restrict__ flag, unsigned short* __restrict__ dst) {
    const int isInt = flag[0];
    const int n = DIM * DIM;
    for (int i = blockIdx.x * 256 + threadIdx.x; i < n; i += gridDim.x * 256) {
        bool m;
        if (isInt) m = ((const int*)mask)[i] != 0;
        else       m = ((const unsigned char*)mask)[i] != 0;
        dst[i] = f2bf(m ? synw[i] : 0.f);
    }
}

// ---------------- f32 -> bf16 convert ----------------
__global__ void conv_k(const float* __restrict__ src, unsigned short* __restrict__ dst, int n) {
    for (int i = blockIdx.x * 256 + threadIdx.x; i < n; i += gridDim.x * 256)
        dst[i] = f2bf(src[i]);
}

// ---------------- f32 -> bf16 hi/lo split ----------------
__global__ void split_k(const float* __restrict__ src, unsigned short* __restrict__ hi,
                        unsigned short* __restrict__ lo, int n) {
    for (int i = blockIdx.x * 256 + threadIdx.x; i < n; i += gridDim.x * 256) {
        float v = src[i];
        unsigned short h = f2bf(v);
        hi[i] = h;
        lo[i] = f2bf(v - bf2f(h));
    }
}

// ---------------- spike bit expansion: u32 bits -> bf16 {0,1} ----------------
__global__ void spkexp_k(const unsigned int* __restrict__ spk, unsigned short* __restrict__ sbf) {
    const int i = blockIdx.x * 256 + threadIdx.x;   // 4*64*1024 words
    const unsigned int w = spk[i];
    const int d = i & 1023, t32 = (i >> 10) & 63, b = i >> 16;
    const size_t base = ((size_t)b * TT + (size_t)t32 * 32) * DIM + d;
    #pragma unroll
    for (int j = 0; j < 32; ++j)
        sbf[base + (size_t)j * DIM] = ((w >> j) & 1u) ? (unsigned short)0x3F80 : (unsigned short)0;
}

// ---------------- rmsnorm; SPLIT: also emit lo residual ----------------
template <bool SPLIT>
__global__ void rms_k(const float* __restrict__ xin, const float* __restrict__ w,
                      unsigned short* __restrict__ hi, unsigned short* __restrict__ lo) {
    const int row = blockIdx.x;
    const int tid = threadIdx.x;
    const float4 xv = *reinterpret_cast<const float4*>(xin + (size_t)row * DIM + tid * 4);
    float ss = xv.x * xv.x + xv.y * xv.y + xv.z * xv.z + xv.w * xv.w;
    #pragma unroll
    for (int m = 1; m <= 32; m <<= 1) ss += __shfl_xor(ss, m);
    __shared__ float red[5];
    if ((tid & 63) == 0) red[tid >> 6] = ss;
    __syncthreads();
    if (tid == 0) {
        float s = red[0] + red[1] + red[2] + red[3];
        red[4] = 1.f / sqrtf(s * (1.f / DIM) + 1e-6f);
    }
    __syncthreads();
    const float scale = red[4];
    const float wv[4] = {w[tid*4], w[tid*4+1], w[tid*4+2], w[tid*4+3]};
    const float xa[4] = {xv.x, xv.y, xv.z, xv.w};
    #pragma unroll
    for (int i = 0; i < 4; ++i) {
        float v = xa[i] * scale * wv[i];
        unsigned short h = f2bf(v);
        hi[(size_t)row * DIM + tid * 4 + i] = h;
        if constexpr (SPLIT) lo[(size_t)row * DIM + tid * 4 + i] = f2bf(v - bf2f(h));
    }
}

// ---------------- LDS-staged MFMA GEMM (m97 structure): C = A @ B^T --------
template <int EPI>
__global__ __launch_bounds__(256, 1) void gemm2_k(
    const unsigned short* __restrict__ A,  const unsigned short* __restrict__ Alo,
    const unsigned short* __restrict__ B1, const unsigned short* __restrict__ B1lo,
    const unsigned short* __restrict__ B2,
    const float* __restrict__ aux1, const float* __restrict__ aux2,
    float* __restrict__ outf, unsigned short* __restrict__ outbf,
    int N, int K) {
    constexpr bool HILO = (EPI == 0);
    constexpr bool DUAL = (EPI == 1 || EPI == 2);
    __shared__ unsigned short sA[128 * 64];
    __shared__ unsigned short sB1[128 * 64];
    __shared__ unsigned short sAlo[HILO ? 128 * 64 : 8];
    __shared__ unsigned short sBlo[HILO ? 128 * 64 : 8];
    __shared__ unsigned short sB2[DUAL ? 128 * 64 : 8];
    const int lane = threadIdx.x & 63;
    const int wv = threadIdx.x >> 6;
    const int l15 = lane & 15, l4 = lane >> 4;
    const long row0 = (long)blockIdx.y * 128;
    const long col0 = (long)blockIdx.x * 128;
    const int wr = wv >> 1, wc = wv & 1;
    const int crow = lane >> 3;
    const int cbyte = (lane & 7) * 16;
    f32x4 acc[4][4];
    f32x4 acc2[DUAL ? 4 : 1][DUAL ? 4 : 1];
    #pragma unroll
    for (int i = 0; i < 4; ++i)
        #pragma unroll
        for (int j = 0; j < 4; ++j) {
            acc[i][j] = (f32x4){0.f, 0.f, 0.f, 0.f};
            if constexpr (DUAL) acc2[i][j] = (f32x4){0.f, 0.f, 0.f, 0.f};
        }
    for (int kt = 0; kt < K; kt += 64) {
        #pragma unroll
        for (int i = 0; i < 4; ++i) {
            const int chunk = wv * 4 + i;
            const int trow = chunk * 8 + crow;
            const size_t goffA = ((row0 + trow) * (size_t)K + kt) * 2 + cbyte;
            const size_t goffB = ((col0 + trow) * (size_t)K + kt) * 2 + cbyte;
            gload_lds16((const char*)A + goffA, (char*)sA + chunk * 1024);
            gload_lds16((const char*)B1 + goffB, (char*)sB1 + chunk * 1024);
            if constexpr (HILO) {
                gload_lds16((const char*)Alo + goffA, (char*)sAlo + chunk * 1024);
                gload_lds16((const char*)B1lo + goffB, (char*)sBlo + chunk * 1024);
            }
            if constexpr (DUAL)
                gload_lds16((const char*)B2 + goffB, (char*)sB2 + chunk * 1024);
        }
        __syncthreads();
        #pragma unroll
        for (int kk2 = 0; kk2 < 64; kk2 += 32) {
            bf16x8 af[4], bf_[4], al[4], bl[4], b2f[4];
            #pragma unroll
            for (int i = 0; i < 4; ++i) {
                const int ao = (wr * 64 + i * 16 + l15) * 64 + kk2 + l4 * 8;
                const int bo = (wc * 64 + i * 16 + l15) * 64 + kk2 + l4 * 8;
                af[i]  = ldf(sA + ao);
                bf_[i] = ldf(sB1 + bo);
                if constexpr (HILO) { al[i] = ldf(sAlo + ao); bl[i] = ldf(sBlo + bo); }
                if constexpr (DUAL) b2f[i] = ldf(sB2 + bo);
            }
            #pragma unroll
            for (int i = 0; i < 4; ++i)
                #pragma unroll
                for (int j = 0; j < 4; ++j) {
                    acc[i][j] = __builtin_amdgcn_mfma_f32_16x16x32_bf16(af[i], bf_[j], acc[i][j], 0, 0, 0);
                    if constexpr (HILO) {
                        acc[i][j] = __builtin_amdgcn_mfma_f32_16x16x32_bf16(af[i], bl[j], acc[i][j], 0, 0, 0);
                        acc[i][j] = __builtin_amdgcn_mfma_f32_16x16x32_bf16(al[i], bf_[j], acc[i][j], 0, 0, 0);
                    }
                    if constexpr (DUAL)
                        acc2[i][j] = __builtin_amdgcn_mfma_f32_16x16x32_bf16(af[i], b2f[j], acc2[i][j], 0, 0, 0);
                }
        }
        __syncthreads();
    }
    #pragma unroll
    for (int i = 0; i < 4; ++i) {
        #pragma unroll
        for (int r = 0; r < 4; ++r) {
            const long row = row0 + wr * 64 + i * 16 + l4 * 4 + r;
            #pragma unroll
            for (int j = 0; j < 4; ++j) {
                const long col = col0 + wc * 64 + j * 16 + l15;
                float v = acc[i][j][r];
                if constexpr (EPI == 0) {
                    int m = (int)row;
                    int bb = m >> 11, tt = m & 2047;
                    outf[((size_t)(tt * NBATCH + bb)) * DIM + col] = v + aux1[col];
                } else if constexpr (EPI == 1) {
                    size_t idx = (size_t)row * N + col;
                    float gg = acc2[i][j][r] + aux2[col];
                    outf[idx] = aux1[idx] + v * (1.f / (1.f + expf(-gg)));
                } else if constexpr (EPI == 2) {
                    size_t idx = (size_t)row * N + col;
                    float u = acc2[i][j][r];
                    outbf[idx] = f2bf((v / (1.f + expf(-v))) * u);
                } else {
                    size_t idx = (size_t)row * N + col;
                    outf[idx] = aux1[idx] + v;
                }
            }
        }
    }
}

// ---------------- liquid recurrence + PLIF, 64 co-resident WGs --------------
// R9/R13 sync protocol UNCHANGED (barrier -> tid0 single flag -> one wave-0
// poller/WG scalar-dword poll -> barrier -> refill -> barrier). Compute side
// restructured: WG owns (32 dims x 2 batches); per-thread LDS reads halve
// (8 ds_read_b128) and FMAs halve (128). Poll set = 64 flags (256 B), lane L
// covers flags[L] -- same aggregate poll bytes/round as R13.
// LDS h layout (bijective): word(bb,k) = bb*1088 + (k>>6)*68 + (k&63)
__global__ __launch_bounds__(512, 1) void recur_k(
    const float* __restrict__ wrec, const float* __restrict__ U,
    const float* __restrict__ liqtau, const float* __restrict__ plifw,
    float* __restrict__ hg, int* __restrict__ flags, unsigned int* __restrict__ spk) {
    const int tid = threadIdx.x;
    const int wg = blockIdx.x;
    const int g = tid >> 6;
    const int L = tid & 63;
    const int kp = L;
    const int d0 = (wg >> 1) * 32 + g * 4;   // 4 dims per wave
    const int bp = (wg & 1) * 2;             // batch pair {bp, bp+1}

    float wreg[4][16];
    #pragma unroll
    for (int d = 0; d < 4; ++d) {
        const float* wr = wrec + (size_t)(d0 + d) * DIM + kp * 16;
        #pragma unroll
        for (int q = 0; q < 4; ++q) {
            f32x4 w4 = *reinterpret_cast<const f32x4*>(wr + q * 4);
            wreg[d][q*4+0] = w4[0]; wreg[d][q*4+1] = w4[1];
            wreg[d][q*4+2] = w4[2]; wreg[d][q*4+3] = w4[3];
        }
    }

    __shared__ float hl[2 * 1088];
    for (int i = tid; i < 2 * 1088; i += 512) hl[i] = 0.f;

    const int od = L >> 1, obl = L & 1;      // own: dim-in-wave, local batch
    const int ob = bp + obl;                 // global batch
    const int odim = d0 + od;
    const bool own = (L < 8);
    float hq = 0.f, vq = 0.f, tauv = 1.f;
    unsigned smask = 0u;
    const float decay = 1.f / (1.f + expf(-plifw[0]));
    if (own) {
        float lt = liqtau[odim];
        tauv = (lt > 20.f) ? lt : log1pf(expf(lt));
    }
    const int sel1 = L & 1, sel2 = (L >> 1) & 1, sel4 = (L >> 2) & 1;

    int cb[2];
    #pragma unroll
    for (int b = 0; b < 2; ++b)
        cb[b] = b * 1088 + (kp >> 2) * 68 + (kp & 3) * 16;
    // refill: thread covers bb = tid>>8, k0 = (tid&255)*4  (one dwordx4)
    const int rbb = tid >> 8, rk0 = (tid & 255) * 4;
    const int rw = rbb * 1088 + (rk0 >> 6) * 68 + (rk0 & 63);
    __syncthreads();

    for (int t = 0; t < TT; ++t) {
        float uvp = 0.f;
        if (own) uvp = U[((size_t)t * NBATCH + ob) * DIM + odim];

        // a[v], v = d*2 + b_local
        float a[8];
        #pragma unroll
        for (int v = 0; v < 8; ++v) a[v] = 0.f;
        #pragma unroll
        for (int q = 0; q < 4; ++q) {
            const f32x4 h0 = *reinterpret_cast<const f32x4*>(hl + cb[0] + q * 4);
            const f32x4 h1 = *reinterpret_cast<const f32x4*>(hl + cb[1] + q * 4);
            #pragma unroll
            for (int d = 0; d < 4; ++d)
                #pragma unroll
                for (int e = 0; e < 4; ++e) {
                    const float w = wreg[d][q * 4 + e];
                    a[d*2+0] = fmaf(w, h0[e], a[d*2+0]);
                    a[d*2+1] = fmaf(w, h1[e], a[d*2+1]);
                }
        }
        // butterfly-scatter reduce (8 values): lane L ends with sum(a[L&7])
        #pragma unroll
        for (int j = 0; j < 4; ++j) {
            float snd = sel1 ? a[2*j] : a[2*j+1];
            float kept = sel1 ? a[2*j+1] : a[2*j];
            a[j] = kept + __shfl_xor(snd, 1);
        }
        #pragma unroll
        for (int j = 0; j < 2; ++j) {
            float snd = sel2 ? a[2*j] : a[2*j+1];
            float kept = sel2 ? a[2*j+1] : a[2*j];
            a[j] = kept + __shfl_xor(snd, 2);
        }
        {
            float snd = sel4 ? a[0] : a[1];
            float kept = sel4 ? a[1] : a[0];
            a[0] = kept + __shfl_xor(snd, 4);
        }
        a[0] += __shfl_xor(a[0], 8);
        a[0] += __shfl_xor(a[0], 16);
        a[0] += __shfl_xor(a[0], 32);

        if (own) {
            float pre = a[0] + uvp;
            float th = tanhf(pre);
            float hn = hq + (th - hq) / tauv;
            hq = hn;
            float v = vq + decay * (hn - vq);
            float s = ((v - THRESH) > 0.f) ? 1.f : 0.f;
            vq = v - s * THRESH;
            smask |= (s > 0.f ? 1u : 0u) << (t & 31);
            if ((t & 31) == 31) {
                __hip_atomic_store(&spk[ob * 65536 + (t >> 5) * 1024 + odim], smask,
                                   __ATOMIC_RELAXED, __HIP_MEMORY_SCOPE_SYSTEM);
                smask = 0u;
            }
            // write-through to MALL (sc0 sc1); acked before barrier releases
            __hip_atomic_store(&hg[(size_t)(t & 1) * 4096 + ob * 1024 + odim], hn,
                               __ATOMIC_RELAXED, __HIP_MEMORY_SCOPE_SYSTEM);
        }
        if (t == TT - 1) break;
        __syncthreads();  // per-wave vmcnt(0): all write-through h stores at MALL
        if (tid == 0)     // RELAXED single flag per WG (R9-proven)
            __hip_atomic_store(&flags[wg], t + 1, __ATOMIC_RELAXED, __HIP_MEMORY_SCOPE_SYSTEM);
        if (g == 0) {
            while (__hip_atomic_load(&flags[L], __ATOMIC_RELAXED,
                                     __HIP_MEMORY_SCOPE_SYSTEM) < t + 1) {}
        }
        __syncthreads();
        {
            const float* src = hg + (size_t)(t & 1) * 4096 + (bp + rbb) * 1024 + rk0;
            f32x4 va;
            ld1x4_mall(src, &va);
            *reinterpret_cast<f32x4*>(hl + rw) = va;
        }
        __syncthreads();
    }
}

extern "C" void kernel_launch(void* const* d_in, const int* in_sizes, int n_in,
                              void* d_out, int out_size, void* d_ws, size_t ws_size,
                              hipStream_t stream) {
    (void)in_sizes; (void)n_in; (void)out_size;
    const float* x     = (const float*)d_in[0];
    const float* ln1   = (const float*)d_in[1];
    const float* win   = (const float*)d_in[2];
    const float* wrec  = (const float*)d_in[3];
    const float* liqb  = (const float*)d_in[4];
    const float* liqtau= (const float*)d_in[5];
    const float* plifw = (const float*)d_in[6];
    const float* synw  = (const float*)d_in[7];
    const float* gatew = (const float*)d_in[8];
    const float* gateb = (const float*)d_in[9];
    const float* ln2   = (const float*)d_in[10];
    const float* wgp   = (const float*)d_in[11];
    const float* wup   = (const float*)d_in[12];
    const float* wdp   = (const float*)d_in[13];
    const void*  mask  = d_in[14];
    float* dout = (float*)d_out;
    char* ws = (char*)d_ws;
    const size_t MB = (size_t)1 << 20;

    unsigned short* winh  = (unsigned short*)(ws + 0 * MB);
    unsigned short* winl  = (unsigned short*)(ws + 2 * MB);
    unsigned short* weffb = (unsigned short*)(ws + 4 * MB);
    unsigned short* gatewb= (unsigned short*)(ws + 6 * MB);
    unsigned short* wgb   = (unsigned short*)(ws + 8 * MB);
    unsigned short* wub   = (unsigned short*)(ws + 24 * MB);
    unsigned short* wdb   = (unsigned short*)(ws + 40 * MB);
    unsigned short* ahi   = (unsigned short*)(ws + 56 * MB);   // reused as y_bf
    unsigned short* alo   = (unsigned short*)(ws + 72 * MB);
    float*          Ubuf  = (float*)(ws + 88 * MB);            // reused as hff chunk
    unsigned short* hffb  = (unsigned short*)(ws + 88 * MB);
    unsigned short* sbf   = (unsigned short*)(ws + 120 * MB);
    float*          x2    = (float*)(ws + 136 * MB);
    float*          hgb   = (float*)(ws + 168 * MB);           // 32 KB
    int*            flags = (int*)(ws + 168 * MB + 64 * 1024); // 256 B (64 flags)
    int*            flag  = (int*)(ws + 168 * MB + 80 * 1024);
    unsigned int*   spk   = (unsigned int*)(ws + 169 * MB);    // 1 MB
    unsigned short* hfull = (unsigned short*)(ws + 171 * MB);  // 128 MiB if avail
    const bool FULLFFN = (ws_size >= 306 * MB);

    hipMemsetAsync(flags, 0, 1024, stream);
    maskprobe_k<<<1, 256, 0, stream>>>((const unsigned int*)mask, flag);
    weff_k<<<1024, 256, 0, stream>>>(synw, mask, flag, weffb);
    split_k<<<1024, 256, 0, stream>>>(win, winh, winl, DIM * DIM);
    conv_k<<<1024, 256, 0, stream>>>(gatew, gatewb, DIM * DIM);
    conv_k<<<2048, 256, 0, stream>>>(wgp, wgb, HFF * DIM);
    conv_k<<<2048, 256, 0, stream>>>(wup, wub, HFF * DIM);
    conv_k<<<2048, 256, 0, stream>>>(wdp, wdb, DIM * HFF);

    rms_k<true><<<NBATCH * TT, 256, 0, stream>>>(x, ln1, ahi, alo);
    gemm2_k<0><<<dim3(DIM / 128, (NBATCH * TT) / 128), 256, 0, stream>>>(
        ahi, alo, winh, winl, nullptr, liqb, nullptr, Ubuf, nullptr, DIM, DIM);

    recur_k<<<PWG, 512, 0, stream>>>(wrec, Ubuf, liqtau, plifw, hgb, flags, spk);
    spkexp_k<<<(NBATCH * 64 * 1024) / 256, 256, 0, stream>>>(spk, sbf);

    gemm2_k<1><<<dim3(DIM / 128, (NBATCH * TT) / 128), 256, 0, stream>>>(
        sbf, nullptr, weffb, nullptr, gatewb, x, gateb, x2, nullptr, DIM, DIM);

    rms_k<false><<<NBATCH * TT, 256, 0, stream>>>(x2, ln2, ahi, nullptr);

    if (FULLFFN) {
        gemm2_k<2><<<dim3(HFF / 128, (NBATCH * TT) / 128), 256, 0, stream>>>(
            ahi, nullptr, wgb, nullptr, wub, nullptr, nullptr,
            nullptr, hfull, HFF, DIM);
        gemm2_k<3><<<dim3(DIM / 128, (NBATCH * TT) / 128), 256, 0, stream>>>(
            hfull, nullptr, wdb, nullptr, nullptr, x2, nullptr,
            dout, nullptr, DIM, HFF);
    } else {
        const int CH = 2048;  // fallback: chunked FFN bounded to 32 MB scratch
        for (int c = 0; c < (NBATCH * TT) / CH; ++c) {
            const size_t ro = (size_t)c * CH;
            gemm2_k<2><<<dim3(HFF / 128, CH / 128), 256, 0, stream>>>(
                ahi + ro * DIM, nullptr, wgb, nullptr, wub, nullptr, nullptr,
                nullptr, hffb, HFF, DIM);
            gemm2_k<3><<<dim3(DIM / 128, CH / 128), 256, 0, stream>>>(
                hffb, nullptr, wdb, nullptr, nullptr, x2 + ro * DIM, nullptr,
                dout + ro * DIM, nullptr, DIM, HFF);
        }
    }
}

// Round 16
// 7535.985 us; speedup vs baseline: 1.4625x; 1.2102x over previous
//
#include <hip/hip_runtime.h>
#include <hip/hip_bf16.h>

#define TT 2048
#define DIM 1024
#define HFF 8192
#define NBATCH 4
#define PWG 32
#define THRESH 0.05f

typedef __bf16 bf16x8 __attribute__((ext_vector_type(8)));
typedef float f32x4 __attribute__((ext_vector_type(4)));

__device__ __forceinline__ unsigned short f2bf(float f) {
    __hip_bfloat16 h = __float2bfloat16(f);
    return __builtin_bit_cast(unsigned short, h);
}
__device__ __forceinline__ float bf2f(unsigned short u) {
    return __bfloat162float(__builtin_bit_cast(__hip_bfloat16, u));
}
__device__ __forceinline__ bf16x8 ldf(const unsigned short* p) {
    return *reinterpret_cast<const bf16x8*>(p);
}

// MALL-coherent (cross-XCD) 16B load: bypass L1 (sc0) and L2 (sc1).
__device__ __forceinline__ void ld2x4_mall(const float* p0, const float* p1,
                                           f32x4* a, f32x4* b) {
    asm volatile("global_load_dwordx4 %0, %2, off sc0 sc1\n\t"
                 "global_load_dwordx4 %1, %3, off sc0 sc1\n\t"
                 "s_waitcnt vmcnt(0)"
                 : "=&v"(*a), "=&v"(*b) : "v"(p0), "v"(p1) : "memory");
}

// async global->LDS, 16B per lane; LDS dest = (uniform base) + lane*16
__device__ __forceinline__ void gload_lds16(const void* g, void* l) {
    __builtin_amdgcn_global_load_lds(
        (const __attribute__((address_space(1))) unsigned int*)g,
        (__attribute__((address_space(3))) unsigned int*)l, 16, 0, 0);
}

// ---------------- mask dtype probe: 1 = int32 mask, 0 = uint8 mask ----------
__global__ void maskprobe_k(const unsigned int* mask_words, int* flag) {
    __shared__ int allok;
    if (threadIdx.x == 0) allok = 1;
    __syncthreads();
    int ok = 1;
    for (int i = 0; i < 16; ++i) {
        unsigned int w = mask_words[threadIdx.x * 16 + i];
        if (w > 1u) ok = 0;
    }
    if (!ok) atomicAnd(&allok, 0);
    __syncthreads();
    if (threadIdx.x == 0) flag[0] = allok;
}

// ---------------- w_eff = syn_w * mask  -> bf16 ----------------
__global__ void weff_k(const float* __restrict__ synw, const void* __restrict__ mask,
                       const int* __restrict__ flag, unsigned short* __restrict__ dst) {
    const int isInt = flag[0];
    const int n = DIM * DIM;
    for (int i = blockIdx.x * 256 + threadIdx.x; i < n; i += gridDim.x * 256) {
        bool m;
        if (isInt) m = ((const int*)mask)[i] != 0;
        else       m = ((const unsigned char*)mask)[i] != 0;
        dst[i] = f2bf(m ? synw[i] : 0.f);
    }
}

// ---------------- f32 -> bf16 convert ----------------
__global__ void conv_k(const float* __restrict__ src, unsigned short* __restrict__ dst, int n) {
    for (int i = blockIdx.x * 256 + threadIdx.x; i < n; i += gridDim.x * 256)
        dst[i] = f2bf(src[i]);
}

// ---------------- f32 -> bf16 hi/lo split ----------------
__global__ void split_k(const float* __restrict__ src, unsigned short* __restrict__ hi,
                        unsigned short* __restrict__ lo, int n) {
    for (int i = blockIdx.x * 256 + threadIdx.x; i < n; i += gridDim.x * 256) {
        float v = src[i];
        unsigned short h = f2bf(v);
        hi[i] = h;
        lo[i] = f2bf(v - bf2f(h));
    }
}

// ---------------- spike bit expansion: u32 bits -> bf16 {0,1} ----------------
__global__ void spkexp_k(const unsigned int* __restrict__ spk, unsigned short* __restrict__ sbf) {
    const int i = blockIdx.x * 256 + threadIdx.x;   // 4*64*1024 words
    const unsigned int w = spk[i];
    const int d = i & 1023, t32 = (i >> 10) & 63, b = i >> 16;
    const size_t base = ((size_t)b * TT + (size_t)t32 * 32) * DIM + d;
    #pragma unroll
    for (int j = 0; j < 32; ++j)
        sbf[base + (size_t)j * DIM] = ((w >> j) & 1u) ? (unsigned short)0x3F80 : (unsigned short)0;
}

// ---------------- rmsnorm; SPLIT: also emit lo residual ----------------
template <bool SPLIT>
__global__ void rms_k(const float* __restrict__ xin, const float* __restrict__ w,
                      unsigned short* __restrict__ hi, unsigned short* __restrict__ lo) {
    const int row = blockIdx.x;
    const int tid = threadIdx.x;
    const float4 xv = *reinterpret_cast<const float4*>(xin + (size_t)row * DIM + tid * 4);
    float ss = xv.x * xv.x + xv.y * xv.y + xv.z * xv.z + xv.w * xv.w;
    #pragma unroll
    for (int m = 1; m <= 32; m <<= 1) ss += __shfl_xor(ss, m);
    __shared__ float red[5];
    if ((tid & 63) == 0) red[tid >> 6] = ss;
    __syncthreads();
    if (tid == 0) {
        float s = red[0] + red[1] + red[2] + red[3];
        red[4] = 1.f / sqrtf(s * (1.f / DIM) + 1e-6f);
    }
    __syncthreads();
    const float scale = red[4];
    const float wv[4] = {w[tid*4], w[tid*4+1], w[tid*4+2], w[tid*4+3]};
    const float xa[4] = {xv.x, xv.y, xv.z, xv.w};
    #pragma unroll
    for (int i = 0; i < 4; ++i) {
        float v = xa[i] * scale * wv[i];
        unsigned short h = f2bf(v);
        hi[(size_t)row * DIM + tid * 4 + i] = h;
        if constexpr (SPLIT) lo[(size_t)row * DIM + tid * 4 + i] = f2bf(v - bf2f(h));
    }
}

// ---------------- LDS-staged MFMA GEMM (m97 structure): C = A @ B^T --------
template <int EPI>
__global__ __launch_bounds__(256, 1) void gemm2_k(
    const unsigned short* __restrict__ A,  const unsigned short* __restrict__ Alo,
    const unsigned short* __restrict__ B1, const unsigned short* __restrict__ B1lo,
    const unsigned short* __restrict__ B2,
    const float* __restrict__ aux1, const float* __restrict__ aux2,
    float* __restrict__ outf, unsigned short* __restrict__ outbf,
    int N, int K) {
    constexpr bool HILO = (EPI == 0);
    constexpr bool DUAL = (EPI == 1 || EPI == 2);
    __shared__ unsigned short sA[128 * 64];
    __shared__ unsigned short sB1[128 * 64];
    __shared__ unsigned short sAlo[HILO ? 128 * 64 : 8];
    __shared__ unsigned short sBlo[HILO ? 128 * 64 : 8];
    __shared__ unsigned short sB2[DUAL ? 128 * 64 : 8];
    const int lane = threadIdx.x & 63;
    const int wv = threadIdx.x >> 6;
    const int l15 = lane & 15, l4 = lane >> 4;
    const long row0 = (long)blockIdx.y * 128;
    const long col0 = (long)blockIdx.x * 128;
    const int wr = wv >> 1, wc = wv & 1;
    const int crow = lane >> 3;
    const int cbyte = (lane & 7) * 16;
    f32x4 acc[4][4];
    f32x4 acc2[DUAL ? 4 : 1][DUAL ? 4 : 1];
    #pragma unroll
    for (int i = 0; i < 4; ++i)
        #pragma unroll
        for (int j = 0; j < 4; ++j) {
            acc[i][j] = (f32x4){0.f, 0.f, 0.f, 0.f};
            if constexpr (DUAL) acc2[i][j] = (f32x4){0.f, 0.f, 0.f, 0.f};
        }
    for (int kt = 0; kt < K; kt += 64) {
        #pragma unroll
        for (int i = 0; i < 4; ++i) {
            const int chunk = wv * 4 + i;
            const int trow = chunk * 8 + crow;
            const size_t goffA = ((row0 + trow) * (size_t)K + kt) * 2 + cbyte;
            const size_t goffB = ((col0 + trow) * (size_t)K + kt) * 2 + cbyte;
            gload_lds16((const char*)A + goffA, (char*)sA + chunk * 1024);
            gload_lds16((const char*)B1 + goffB, (char*)sB1 + chunk * 1024);
            if constexpr (HILO) {
                gload_lds16((const char*)Alo + goffA, (char*)sAlo + chunk * 1024);
                gload_lds16((const char*)B1lo + goffB, (char*)sBlo + chunk * 1024);
            }
            if constexpr (DUAL)
                gload_lds16((const char*)B2 + goffB, (char*)sB2 + chunk * 1024);
        }
        __syncthreads();
        #pragma unroll
        for (int kk2 = 0; kk2 < 64; kk2 += 32) {
            bf16x8 af[4], bf_[4], al[4], bl[4], b2f[4];
            #pragma unroll
            for (int i = 0; i < 4; ++i) {
                const int ao = (wr * 64 + i * 16 + l15) * 64 + kk2 + l4 * 8;
                const int bo = (wc * 64 + i * 16 + l15) * 64 + kk2 + l4 * 8;
                af[i]  = ldf(sA + ao);
                bf_[i] = ldf(sB1 + bo);
                if constexpr (HILO) { al[i] = ldf(sAlo + ao); bl[i] = ldf(sBlo + bo); }
                if constexpr (DUAL) b2f[i] = ldf(sB2 + bo);
            }
            #pragma unroll
            for (int i = 0; i < 4; ++i)
                #pragma unroll
                for (int j = 0; j < 4; ++j) {
                    acc[i][j] = __builtin_amdgcn_mfma_f32_16x16x32_bf16(af[i], bf_[j], acc[i][j], 0, 0, 0);
                    if constexpr (HILO) {
                        acc[i][j] = __builtin_amdgcn_mfma_f32_16x16x32_bf16(af[i], bl[j], acc[i][j], 0, 0, 0);
                        acc[i][j] = __builtin_amdgcn_mfma_f32_16x16x32_bf16(al[i], bf_[j], acc[i][j], 0, 0, 0);
                    }
                    if constexpr (DUAL)
                        acc2[i][j] = __builtin_amdgcn_mfma_f32_16x16x32_bf16(af[i], b2f[j], acc2[i][j], 0, 0, 0);
                }
        }
        __syncthreads();
    }
    #pragma unroll
    for (int i = 0; i < 4; ++i) {
        #pragma unroll
        for (int r = 0; r < 4; ++r) {
            const long row = row0 + wr * 64 + i * 16 + l4 * 4 + r;
            #pragma unroll
            for (int j = 0; j < 4; ++j) {
                const long col = col0 + wc * 64 + j * 16 + l15;
                float v = acc[i][j][r];
                if constexpr (EPI == 0) {
                    int m = (int)row;
                    int bb = m >> 11, tt = m & 2047;
                    outf[((size_t)(tt * NBATCH + bb)) * DIM + col] = v + aux1[col];
                } else if constexpr (EPI == 1) {
                    size_t idx = (size_t)row * N + col;
                    float gg = acc2[i][j][r] + aux2[col];
                    outf[idx] = aux1[idx] + v * (1.f / (1.f + expf(-gg)));
                } else if constexpr (EPI == 2) {
                    size_t idx = (size_t)row * N + col;
                    float u = acc2[i][j][r];
                    outbf[idx] = f2bf((v / (1.f + expf(-v))) * u);
                } else {
                    size_t idx = (size_t)row * N + col;
                    outf[idx] = aux1[idx] + v;
                }
            }
        }
    }
}

// ---------------- liquid recurrence + PLIF, 32 co-resident WGs --------------
// Sync: byte-identical R13 (barrier -> tid0 flag -> wave-0 polls 32 flags ->
// barrier -> refill -> barrier). Compute: wave g owns (8 dims x 2 batches):
// dims wg*32+(g&3)*8+{0..7}, batches (g>>2)*2+{0,1}. Per-thread LDS reads
// halve vs R13 (2 batches x 16k = 8 ds_read_b128); FMAs unchanged (256).
// Reduce: proven 16-value butterfly-scatter; lane L<16 owns d=L>>1, bl=L&1.
// LDS h layout (bijective): word(b,k) = b*1088 + (k>>6)*68 + (k&63)
__global__ __launch_bounds__(512, 1) void recur_k(
    const float* __restrict__ wrec, const float* __restrict__ U,
    const float* __restrict__ liqtau, const float* __restrict__ plifw,
    float* __restrict__ hg, int* __restrict__ flags, unsigned int* __restrict__ spk) {
    const int tid = threadIdx.x;
    const int wg = blockIdx.x;
    const int g = tid >> 6;
    const int L = tid & 63;
    const int kp = L;
    const int d0 = wg * 32 + (g & 3) * 8;    // 8 dims per wave
    const int bg = (g >> 2) * 2;             // wave's batch pair base

    float wreg[8][16];
    #pragma unroll
    for (int d = 0; d < 8; ++d) {
        const float* wr = wrec + (size_t)(d0 + d) * DIM + kp * 16;
        #pragma unroll
        for (int q = 0; q < 4; ++q) {
            f32x4 w4 = *reinterpret_cast<const f32x4*>(wr + q * 4);
            wreg[d][q*4+0] = w4[0]; wreg[d][q*4+1] = w4[1];
            wreg[d][q*4+2] = w4[2]; wreg[d][q*4+3] = w4[3];
        }
    }

    __shared__ float hl[4 * 1088];
    for (int i = tid; i < 4 * 1088; i += 512) hl[i] = 0.f;

    const int od = L >> 1, obl = L & 1;      // owner: dim-in-wave, local batch
    const int ob = bg + obl;                 // global batch
    const int odim = d0 + od;
    const bool own = (L < 16);
    float hq = 0.f, vq = 0.f, tauv = 1.f;
    unsigned smask = 0u;
    const float decay = 1.f / (1.f + expf(-plifw[0]));
    if (own) {
        float lt = liqtau[odim];
        tauv = (lt > 20.f) ? lt : log1pf(expf(lt));
    }
    const int sel1 = L & 1, sel2 = (L >> 1) & 1, sel4 = (L >> 2) & 1, sel8 = (L >> 3) & 1;

    int cb[2];
    #pragma unroll
    for (int b = 0; b < 2; ++b)
        cb[b] = (bg + b) * 1088 + (kp >> 2) * 68 + (kp & 3) * 16;
    __syncthreads();

    for (int t = 0; t < TT; ++t) {
        float uvp = 0.f;
        if (own) uvp = U[((size_t)t * NBATCH + ob) * DIM + odim];

        // a[v], v = d*2 + bl  (16 values)
        float a[16];
        #pragma unroll
        for (int v = 0; v < 16; ++v) a[v] = 0.f;
        #pragma unroll
        for (int q = 0; q < 4; ++q) {
            const f32x4 h0 = *reinterpret_cast<const f32x4*>(hl + cb[0] + q * 4);
            const f32x4 h1 = *reinterpret_cast<const f32x4*>(hl + cb[1] + q * 4);
            #pragma unroll
            for (int d = 0; d < 8; ++d)
                #pragma unroll
                for (int e = 0; e < 4; ++e) {
                    const float w = wreg[d][q * 4 + e];
                    a[d*2+0] = fmaf(w, h0[e], a[d*2+0]);
                    a[d*2+1] = fmaf(w, h1[e], a[d*2+1]);
                }
        }
        // butterfly-scatter reduce: lane L ends with sum_lanes(a[L&15]) in a[0]
        #pragma unroll
        for (int j = 0; j < 8; ++j) {
            float snd = sel1 ? a[2*j] : a[2*j+1];
            float kept = sel1 ? a[2*j+1] : a[2*j];
            a[j] = kept + __shfl_xor(snd, 1);
        }
        #pragma unroll
        for (int j = 0; j < 4; ++j) {
            float snd = sel2 ? a[2*j] : a[2*j+1];
            float kept = sel2 ? a[2*j+1] : a[2*j];
            a[j] = kept + __shfl_xor(snd, 2);
        }
        #pragma unroll
        for (int j = 0; j < 2; ++j) {
            float snd = sel4 ? a[2*j] : a[2*j+1];
            float kept = sel4 ? a[2*j+1] : a[2*j];
            a[j] = kept + __shfl_xor(snd, 4);
        }
        {
            float snd = sel8 ? a[0] : a[1];
            float kept = sel8 ? a[1] : a[0];
            a[0] = kept + __shfl_xor(snd, 8);
        }
        a[0] += __shfl_xor(a[0], 16);
        a[0] += __shfl_xor(a[0], 32);

        if (own) {
            float pre = a[0] + uvp;
            float th = tanhf(pre);
            float hn = hq + (th - hq) / tauv;
            hq = hn;
            float v = vq + decay * (hn - vq);
            float s = ((v - THRESH) > 0.f) ? 1.f : 0.f;
            vq = v - s * THRESH;
            smask |= (s > 0.f ? 1u : 0u) << (t & 31);
            if ((t & 31) == 31) {
                __hip_atomic_store(&spk[ob * 65536 + (t >> 5) * 1024 + odim], smask,
                                   __ATOMIC_RELAXED, __HIP_MEMORY_SCOPE_SYSTEM);
                smask = 0u;
            }
            // write-through to MALL (sc0 sc1); acked before barrier releases
            __hip_atomic_store(&hg[(size_t)(t & 1) * 4096 + ob * 1024 + odim], hn,
                               __ATOMIC_RELAXED, __HIP_MEMORY_SCOPE_SYSTEM);
        }
        if (t == TT - 1) break;
        __syncthreads();  // per-wave vmcnt(0): all write-through h stores at MALL
        if (tid == 0)     // RELAXED single flag per WG (R9-proven)
            __hip_atomic_store(&flags[wg], t + 1, __ATOMIC_RELAXED, __HIP_MEMORY_SCOPE_SYSTEM);
        if (g == 0) {
            while (__hip_atomic_load(&flags[L & 31], __ATOMIC_RELAXED,
                                     __HIP_MEMORY_SCOPE_SYSTEM) < t + 1) {}
        }
        __syncthreads();
        {
            const float* src = hg + (size_t)(t & 1) * 4096;
            const int b = tid >> 7, k0 = (tid & 127) * 8;
            const int w = b * 1088 + (k0 >> 6) * 68 + (k0 & 63);
            f32x4 va, vb;
            ld2x4_mall(src + b * 1024 + k0, src + b * 1024 + k0 + 4, &va, &vb);
            *reinterpret_cast<f32x4*>(hl + w) = va;
            *reinterpret_cast<f32x4*>(hl + w + 4) = vb;
        }
        __syncthreads();
    }
}

extern "C" void kernel_launch(void* const* d_in, const int* in_sizes, int n_in,
                              void* d_out, int out_size, void* d_ws, size_t ws_size,
                              hipStream_t stream) {
    (void)in_sizes; (void)n_in; (void)out_size;
    const float* x     = (const float*)d_in[0];
    const float* ln1   = (const float*)d_in[1];
    const float* win   = (const float*)d_in[2];
    const float* wrec  = (const float*)d_in[3];
    const float* liqb  = (const float*)d_in[4];
    const float* liqtau= (const float*)d_in[5];
    const float* plifw = (const float*)d_in[6];
    const float* synw  = (const float*)d_in[7];
    const float* gatew = (const float*)d_in[8];
    const float* gateb = (const float*)d_in[9];
    const float* ln2   = (const float*)d_in[10];
    const float* wgp   = (const float*)d_in[11];
    const float* wup   = (const float*)d_in[12];
    const float* wdp   = (const float*)d_in[13];
    const void*  mask  = d_in[14];
    float* dout = (float*)d_out;
    char* ws = (char*)d_ws;
    const size_t MB = (size_t)1 << 20;

    unsigned short* winh  = (unsigned short*)(ws + 0 * MB);
    unsigned short* winl  = (unsigned short*)(ws + 2 * MB);
    unsigned short* weffb = (unsigned short*)(ws + 4 * MB);
    unsigned short* gatewb= (unsigned short*)(ws + 6 * MB);
    unsigned short* wgb   = (unsigned short*)(ws + 8 * MB);
    unsigned short* wub   = (unsigned short*)(ws + 24 * MB);
    unsigned short* wdb   = (unsigned short*)(ws + 40 * MB);
    unsigned short* ahi   = (unsigned short*)(ws + 56 * MB);   // reused as y_bf
    unsigned short* alo   = (unsigned short*)(ws + 72 * MB);
    float*          Ubuf  = (float*)(ws + 88 * MB);            // reused as hff chunk
    unsigned short* hffb  = (unsigned short*)(ws + 88 * MB);
    unsigned short* sbf   = (unsigned short*)(ws + 120 * MB);
    float*          x2    = (float*)(ws + 136 * MB);
    float*          hgb   = (float*)(ws + 168 * MB);           // 32 KB
    int*            flags = (int*)(ws + 168 * MB + 64 * 1024); // 128 B
    int*            flag  = (int*)(ws + 168 * MB + 80 * 1024);
    unsigned int*   spk   = (unsigned int*)(ws + 169 * MB);    // 1 MB
    unsigned short* hfull = (unsigned short*)(ws + 171 * MB);  // 128 MiB if avail
    const bool FULLFFN = (ws_size >= 306 * MB);

    hipMemsetAsync(flags, 0, 1024, stream);
    maskprobe_k<<<1, 256, 0, stream>>>((const unsigned int*)mask, flag);
    weff_k<<<1024, 256, 0, stream>>>(synw, mask, flag, weffb);
    split_k<<<1024, 256, 0, stream>>>(win, winh, winl, DIM * DIM);
    conv_k<<<1024, 256, 0, stream>>>(gatew, gatewb, DIM * DIM);
    conv_k<<<2048, 256, 0, stream>>>(wgp, wgb, HFF * DIM);
    conv_k<<<2048, 256, 0, stream>>>(wup, wub, HFF * DIM);
    conv_k<<<2048, 256, 0, stream>>>(wdp, wdb, DIM * HFF);

    rms_k<true><<<NBATCH * TT, 256, 0, stream>>>(x, ln1, ahi, alo);
    gemm2_k<0><<<dim3(DIM / 128, (NBATCH * TT) / 128), 256, 0, stream>>>(
        ahi, alo, winh, winl, nullptr, liqb, nullptr, Ubuf, nullptr, DIM, DIM);

    recur_k<<<PWG, 512, 0, stream>>>(wrec, Ubuf, liqtau, plifw, hgb, flags, spk);
    spkexp_k<<<(NBATCH * 64 * 1024) / 256, 256, 0, stream>>>(spk, sbf);

    gemm2_k<1><<<dim3(DIM / 128, (NBATCH * TT) / 128), 256, 0, stream>>>(
        sbf, nullptr, weffb, nullptr, gatewb, x, gateb, x2, nullptr, DIM, DIM);

    rms_k<false><<<NBATCH * TT, 256, 0, stream>>>(x2, ln2, ahi, nullptr);

    if (FULLFFN) {
        gemm2_k<2><<<dim3(HFF / 128, (NBATCH * TT) / 128), 256, 0, stream>>>(
            ahi, nullptr, wgb, nullptr, wub, nullptr, nullptr,
            nullptr, hfull, HFF, DIM);
        gemm2_k<3><<<dim3(DIM / 128, (NBATCH * TT) / 128), 256, 0, stream>>>(
            hfull, nullptr, wdb, nullptr, nullptr, x2, nullptr,
            dout, nullptr, DIM, HFF);
    } else {
        const int CH = 2048;  // fallback: chunked FFN bounded to 32 MB scratch
        for (int c = 0; c < (NBATCH * TT) / CH; ++c) {
            const size_t ro = (size_t)c * CH;
            gemm2_k<2><<<dim3(HFF / 128, CH / 128), 256, 0, stream>>>(
                ahi + ro * DIM, nullptr, wgb, nullptr, wub, nullptr, nullptr,
                nullptr, hffb, HFF, DIM);
            gemm2_k<3><<<dim3(DIM / 128, CH / 128), 256, 0, stream>>>(
                hffb, nullptr, wdb, nullptr, nullptr, x2 + ro * DIM, nullptr,
                dout + ro * DIM, nullptr, DIM, HFF);
        }
    }
}